// Round 1
// baseline (1082.603 us; speedup 1.0000x reference)
//
#include <hip/hip_runtime.h>
#include <math.h>

#define NN     1000000
#define NUPD   131072
#define HDIM   128
#define DMSG   256
#define BM     64

// ---------------------------------------------------------------------------
// Full-table copy: memory -> out (float4 vectorized, grid-stride)
// ---------------------------------------------------------------------------
__global__ void copy_mem_kernel(const float4* __restrict__ src,
                                float4* __restrict__ dst, long long n4) {
  long long i = (long long)blockIdx.x * blockDim.x + threadIdx.x;
  long long stride = (long long)gridDim.x * blockDim.x;
  for (; i < n4; i += stride) dst[i] = src[i];
}

// ---------------------------------------------------------------------------
// Duplicate resolution: winner[node] = max j with node_ids[j] == node
// (np semantics: last occurrence wins). winner pre-memset to -1 (0xFF).
// ---------------------------------------------------------------------------
__global__ void mark_winner_kernel(const int* __restrict__ ids,
                                   int* __restrict__ w) {
  int j = blockIdx.x * blockDim.x + threadIdx.x;
  if (j < NUPD) atomicMax(&w[ids[j]], j);
}

__device__ __forceinline__ float sigmoidf_fast(float x) {
  return 1.0f / (1.0f + __expf(-x));
}
__device__ __forceinline__ float tanhf_fast(float x) {
  // tanh(x) = 1 - 2/(exp(2x)+1); safe at both tails with __expf.
  return 1.0f - 2.0f / (__expf(2.0f * x) + 1.0f);
}

#define DOT4(w, v) ((w).x*(v).x + (w).y*(v).y + (w).z*(v).z + (w).w*(v).w)

// ---------------------------------------------------------------------------
// GRU update. Block = 512 threads = 8 waves, 64 rows per block (lane == row).
// Wave w owns hidden units [w*16, w*16+16). Per lane: 64 f32 accumulators.
// W accesses are wave-uniform (hu0 via readfirstlane) -> scalar/broadcast.
// x/h rows read per-lane from global; all 8 waves share the same 64 rows so
// lines stay hot in L1/L2.
// ---------------------------------------------------------------------------
__launch_bounds__(512, 1)
__global__ void gru_kernel(const float* __restrict__ memory,
                           const int* __restrict__ node_ids,
                           const float* __restrict__ messages,
                           const float* __restrict__ W_ih,
                           const float* __restrict__ W_hh,
                           const float* __restrict__ b_ih,
                           const float* __restrict__ b_hh,
                           const int* __restrict__ winner,
                           float* __restrict__ out)
{
  const int lane = threadIdx.x & 63;
  const int wave = threadIdx.x >> 6;
  const int hu0  = __builtin_amdgcn_readfirstlane(wave * 16);
  const int row  = blockIdx.x * BM + lane;
  const int id   = node_ids[row];

  const float4* __restrict__ xrow = (const float4*)(messages + (size_t)row * DMSG);
  const float4* __restrict__ hrow = (const float4*)(memory  + (size_t)id  * HDIM);
  const float4* __restrict__ Wi4  = (const float4*)W_ih;
  const float4* __restrict__ Wh4  = (const float4*)W_hh;

  float accr[16], accz[16], accni[16], accnh[16];
#pragma unroll
  for (int i = 0; i < 16; ++i) { accr[i]=0.f; accz[i]=0.f; accni[i]=0.f; accnh[i]=0.f; }

  // ---- gi contributions: W_ih @ x (three gate bands) ----
  for (int k4 = 0; k4 < DMSG/4; ++k4) {
    float4 xv = xrow[k4];
#pragma unroll
    for (int i = 0; i < 16; ++i) {
      float4 w = Wi4[(size_t)(hu0 + i) * (DMSG/4) + k4];
      accr[i] += DOT4(w, xv);
    }
  }
  for (int k4 = 0; k4 < DMSG/4; ++k4) {
    float4 xv = xrow[k4];
#pragma unroll
    for (int i = 0; i < 16; ++i) {
      float4 w = Wi4[(size_t)(hu0 + i + HDIM) * (DMSG/4) + k4];
      accz[i] += DOT4(w, xv);
    }
  }
  for (int k4 = 0; k4 < DMSG/4; ++k4) {
    float4 xv = xrow[k4];
#pragma unroll
    for (int i = 0; i < 16; ++i) {
      float4 w = Wi4[(size_t)(hu0 + i + 2*HDIM) * (DMSG/4) + k4];
      accni[i] += DOT4(w, xv);
    }
  }

  // ---- gh contributions: W_hh @ h (three gate bands) ----
  for (int k4 = 0; k4 < HDIM/4; ++k4) {
    float4 hv = hrow[k4];
#pragma unroll
    for (int i = 0; i < 16; ++i) {
      float4 w = Wh4[(size_t)(hu0 + i) * (HDIM/4) + k4];
      accr[i] += DOT4(w, hv);
    }
  }
  for (int k4 = 0; k4 < HDIM/4; ++k4) {
    float4 hv = hrow[k4];
#pragma unroll
    for (int i = 0; i < 16; ++i) {
      float4 w = Wh4[(size_t)(hu0 + i + HDIM) * (HDIM/4) + k4];
      accz[i] += DOT4(w, hv);
    }
  }
  for (int k4 = 0; k4 < HDIM/4; ++k4) {
    float4 hv = hrow[k4];
#pragma unroll
    for (int i = 0; i < 16; ++i) {
      float4 w = Wh4[(size_t)(hu0 + i + 2*HDIM) * (HDIM/4) + k4];
      accnh[i] += DOT4(w, hv);
    }
  }

  // ---- gate math + predicated scatter (only last duplicate writes) ----
  const bool do_write = (winner[id] == row);
  float* __restrict__ orow = out + (size_t)id * HDIM;
#pragma unroll
  for (int i = 0; i < 16; ++i) {
    const int g = hu0 + i;
    float r  = sigmoidf_fast(accr[i] + b_ih[g]        + b_hh[g]);
    float z  = sigmoidf_fast(accz[i] + b_ih[g + HDIM] + b_hh[g + HDIM]);
    float hn = accnh[i] + b_hh[g + 2*HDIM];
    float n  = tanhf_fast(accni[i] + b_ih[g + 2*HDIM] + r * hn);
    float hv = memory[(size_t)id * HDIM + g];
    float nh = (1.0f - z) * n + z * hv;
    if (do_write) orow[g] = nh;
  }
}

extern "C" void kernel_launch(void* const* d_in, const int* in_sizes, int n_in,
                              void* d_out, int out_size, void* d_ws, size_t ws_size,
                              hipStream_t stream) {
  const float* memory   = (const float*)d_in[0];
  const int*   node_ids = (const int*)  d_in[1];
  const float* messages = (const float*)d_in[2];
  const float* W_ih     = (const float*)d_in[3];
  const float* W_hh     = (const float*)d_in[4];
  const float* b_ih     = (const float*)d_in[5];
  const float* b_hh     = (const float*)d_in[6];
  float* out  = (float*)d_out;
  int* winner = (int*)d_ws;   // NN ints = 4 MB of scratch

  // winner := -1 (0xFFFFFFFF)
  hipMemsetAsync(winner, 0xFF, (size_t)NN * sizeof(int), stream);
  mark_winner_kernel<<<NUPD / 256, 256, 0, stream>>>(node_ids, winner);

  // full-table copy (updated rows overwritten by gru_kernel afterwards)
  long long n4 = (long long)NN * HDIM / 4;
  copy_mem_kernel<<<8192, 256, 0, stream>>>((const float4*)memory,
                                            (float4*)out, n4);

  gru_kernel<<<NUPD / BM, 512, 0, stream>>>(memory, node_ids, messages,
                                            W_ih, W_hh, b_ih, b_hh,
                                            winner, out);
}

// Round 2
// 355.513 us; speedup vs baseline: 3.0452x; 3.0452x over previous
//
#include <hip/hip_runtime.h>
#include <math.h>

#define NN     1000000
#define NUPD   131072
#define HDIM   128
#define DMSG   256
#define GRU_BLOCKS (NUPD / 64)   // 2048
#define COPY_BLOCKS 4096

// ws layout: bf16 W_ih [384*256] at 0; bf16 W_hh [384*128] at WH_OFF; winner[NN] at WIN_OFF
#define WI_OFF  0
#define WH_OFF  (384 * 256 * 2)                 // 196608
#define WIN_OFF (WH_OFF + 384 * 128 * 2)        // 294912

typedef __attribute__((ext_vector_type(8))) short bf16x8;
typedef __attribute__((ext_vector_type(4))) float f32x4;

__device__ __forceinline__ short f2bf(float f) {
  unsigned u = __float_as_uint(f);
  unsigned r = (u + 0x7fffu + ((u >> 16) & 1u)) >> 16;
  return (short)r;
}
__device__ __forceinline__ float sigmoidf_fast(float x) {
  return 1.0f / (1.0f + __expf(-x));
}
__device__ __forceinline__ float tanhf_fast(float x) {
  return 1.0f - 2.0f / (__expf(2.0f * x) + 1.0f);
}

// ---------------------------------------------------------------------------
// winner[node] = max j with node_ids[j]==node  (np last-occurrence-wins)
// ---------------------------------------------------------------------------
__global__ void mark_winner_kernel(const int* __restrict__ ids,
                                   int* __restrict__ w) {
  int j = blockIdx.x * blockDim.x + threadIdx.x;
  if (j < NUPD) atomicMax(&w[ids[j]], j);
}

// ---------------------------------------------------------------------------
// f32 -> bf16 weight conversion (tiny, once per launch)
// ---------------------------------------------------------------------------
__global__ void wconv_kernel(const float* __restrict__ Wi,
                             const float* __restrict__ Wh,
                             short* __restrict__ wi_bf,
                             short* __restrict__ wh_bf) {
  int i = blockIdx.x * blockDim.x + threadIdx.x;
  if (i < 384 * 256) {
    wi_bf[i] = f2bf(Wi[i]);
  } else {
    int j = i - 384 * 256;
    if (j < 384 * 128) wh_bf[j] = f2bf(Wh[j]);
  }
}

// ---------------------------------------------------------------------------
// Fat kernel.
//  blocks [0, GRU_BLOCKS): MFMA GRU update for 64 rows each (writes only
//                          winner rows of out).
//  blocks [GRU_BLOCKS, +COPY_BLOCKS): float4 table copy memory->out,
//                          skipping rows with winner>=0 (disjoint writes).
// ---------------------------------------------------------------------------
__launch_bounds__(512, 2)
__global__ void fat_kernel(const float* __restrict__ memory,
                           const int* __restrict__ node_ids,
                           const float* __restrict__ messages,
                           const short* __restrict__ Wi_bf,
                           const short* __restrict__ Wh_bf,
                           const float* __restrict__ b_ih,
                           const float* __restrict__ b_hh,
                           const int* __restrict__ winner,
                           float* __restrict__ out)
{
  __shared__ short xs[64][DMSG + 8];   // bf16 x tile, padded (+16B -> 4-bank row skew)
  __shared__ short hs[64][HDIM + 8];   // bf16 gathered h tile, padded
  __shared__ int   ids_s[64];
  __shared__ char  flag_s[64];

  const int tid = threadIdx.x;

  if (blockIdx.x >= GRU_BLOCKS) {
    // ---------------- copy path ----------------
    const float4* __restrict__ src4 = (const float4*)memory;
    float4* __restrict__ dst4 = (float4*)out;
    const long long n4 = (long long)NN * (HDIM / 4);            // 32M
    long long i = (long long)(blockIdx.x - GRU_BLOCKS) * 512 + tid;
    const long long stride = (long long)COPY_BLOCKS * 512;
    for (; i < n4; i += stride) {
      int row = (int)(i >> 5);
      if (winner[row] < 0) dst4[i] = src4[i];
    }
    return;
  }

  // ---------------- GRU path ----------------
  const int row0 = blockIdx.x * 64;
  const int lane = tid & 63;
  const int wv   = tid >> 6;

  // ids + winner flags
  if (tid < 64) {
    int id = node_ids[row0 + tid];
    ids_s[tid] = id;
    flag_s[tid] = (winner[id] == row0 + tid) ? 1 : 0;
  }

  // stage x tile: 64 rows x 256 cols f32 -> bf16.  thread: 8 elems/iter, 4 iters
  {
    int r = tid >> 5;            // 0..15
    int c8 = tid & 31;           // col chunk (8 f32)
#pragma unroll
    for (int it = 0; it < 4; ++it) {
      const float4* p4 = (const float4*)(messages + (size_t)(row0 + r + it * 16) * DMSG);
      float4 v0 = p4[c8 * 2];
      float4 v1 = p4[c8 * 2 + 1];
      bf16x8 o;
      o[0] = f2bf(v0.x); o[1] = f2bf(v0.y); o[2] = f2bf(v0.z); o[3] = f2bf(v0.w);
      o[4] = f2bf(v1.x); o[5] = f2bf(v1.y); o[6] = f2bf(v1.z); o[7] = f2bf(v1.w);
      *(bf16x8*)&xs[r + it * 16][c8 * 8] = o;
    }
  }

  // stage h tile: 64 rows x 128 cols gathered f32 -> bf16. thread: 16 elems
  {
    int r = tid >> 3;            // 0..63
    int c16 = (tid & 7) * 16;    // start col
    int id = node_ids[row0 + r];
    const float4* p4 = (const float4*)(memory + (size_t)id * HDIM + c16);
    float4 v0 = p4[0], v1 = p4[1], v2 = p4[2], v3 = p4[3];
    bf16x8 o0, o1;
    o0[0] = f2bf(v0.x); o0[1] = f2bf(v0.y); o0[2] = f2bf(v0.z); o0[3] = f2bf(v0.w);
    o0[4] = f2bf(v1.x); o0[5] = f2bf(v1.y); o0[6] = f2bf(v1.z); o0[7] = f2bf(v1.w);
    o1[0] = f2bf(v2.x); o1[1] = f2bf(v2.y); o1[2] = f2bf(v2.z); o1[3] = f2bf(v2.w);
    o1[4] = f2bf(v3.x); o1[5] = f2bf(v3.y); o1[6] = f2bf(v3.z); o1[7] = f2bf(v3.w);
    *(bf16x8*)&hs[r][c16] = o0;
    *(bf16x8*)&hs[r][c16 + 8] = o1;
  }

  __syncthreads();

  // wave wv owns output hidden-unit band [g0, g0+16)
  const int g0  = __builtin_amdgcn_readfirstlane(wv * 16);
  const int col = lane & 15;     // B col within band == A row within row-tile
  const int kg  = lane >> 4;     // k-group (8 elems each)

  f32x4 acc_r[4]  = {{0,0,0,0},{0,0,0,0},{0,0,0,0},{0,0,0,0}};
  f32x4 acc_z[4]  = {{0,0,0,0},{0,0,0,0},{0,0,0,0},{0,0,0,0}};
  f32x4 acc_in[4] = {{0,0,0,0},{0,0,0,0},{0,0,0,0},{0,0,0,0}};
  f32x4 acc_hn[4] = {{0,0,0,0},{0,0,0,0},{0,0,0,0},{0,0,0,0}};

  // ---- x part: K = 256, bands r/z/n of W_ih ----
  {
    const short* wr = Wi_bf + (size_t)(g0 + col) * DMSG;
    const short* wz = Wi_bf + (size_t)(g0 + 128 + col) * DMSG;
    const short* wn = Wi_bf + (size_t)(g0 + 256 + col) * DMSG;
#pragma unroll
    for (int ks = 0; ks < 8; ++ks) {
      const int ko = ks * 32 + kg * 8;
      bf16x8 br = *(const bf16x8*)(wr + ko);
      bf16x8 bz = *(const bf16x8*)(wz + ko);
      bf16x8 bn = *(const bf16x8*)(wn + ko);
#pragma unroll
      for (int rt = 0; rt < 4; ++rt) {
        bf16x8 a = *(const bf16x8*)&xs[rt * 16 + col][ko];
        acc_r[rt]  = __builtin_amdgcn_mfma_f32_16x16x32_bf16(a, br, acc_r[rt], 0, 0, 0);
        acc_z[rt]  = __builtin_amdgcn_mfma_f32_16x16x32_bf16(a, bz, acc_z[rt], 0, 0, 0);
        acc_in[rt] = __builtin_amdgcn_mfma_f32_16x16x32_bf16(a, bn, acc_in[rt], 0, 0, 0);
      }
    }
  }

  // ---- h part: K = 128, bands r/z/n of W_hh ----
  {
    const short* wr = Wh_bf + (size_t)(g0 + col) * HDIM;
    const short* wz = Wh_bf + (size_t)(g0 + 128 + col) * HDIM;
    const short* wn = Wh_bf + (size_t)(g0 + 256 + col) * HDIM;
#pragma unroll
    for (int ks = 0; ks < 4; ++ks) {
      const int ko = ks * 32 + kg * 8;
      bf16x8 br = *(const bf16x8*)(wr + ko);
      bf16x8 bz = *(const bf16x8*)(wz + ko);
      bf16x8 bn = *(const bf16x8*)(wn + ko);
#pragma unroll
      for (int rt = 0; rt < 4; ++rt) {
        bf16x8 a = *(const bf16x8*)&hs[rt * 16 + col][ko];
        acc_r[rt]  = __builtin_amdgcn_mfma_f32_16x16x32_bf16(a, br, acc_r[rt], 0, 0, 0);
        acc_z[rt]  = __builtin_amdgcn_mfma_f32_16x16x32_bf16(a, bz, acc_z[rt], 0, 0, 0);
        acc_hn[rt] = __builtin_amdgcn_mfma_f32_16x16x32_bf16(a, bn, acc_hn[rt], 0, 0, 0);
      }
    }
  }

  // ---- epilogue: gates + predicated scatter ----
  const int g = g0 + col;
  const float bias_r  = b_ih[g] + b_hh[g];
  const float bias_z  = b_ih[g + 128] + b_hh[g + 128];
  const float bias_in = b_ih[g + 256];
  const float bias_hn = b_hh[g + 256];

#pragma unroll
  for (int rt = 0; rt < 4; ++rt) {
#pragma unroll
    for (int reg = 0; reg < 4; ++reg) {
      const int row = rt * 16 + kg * 4 + reg;       // C/D: row=(lane>>4)*4+reg
      const int id  = ids_s[row];
      float r = sigmoidf_fast(acc_r[rt][reg] + bias_r);
      float z = sigmoidf_fast(acc_z[rt][reg] + bias_z);
      float n = tanhf_fast(acc_in[rt][reg] + bias_in + r * (acc_hn[rt][reg] + bias_hn));
      float h = memory[(size_t)id * HDIM + g];
      float nh = (1.0f - z) * n + z * h;
      if (flag_s[row]) out[(size_t)id * HDIM + g] = nh;
    }
  }
}

extern "C" void kernel_launch(void* const* d_in, const int* in_sizes, int n_in,
                              void* d_out, int out_size, void* d_ws, size_t ws_size,
                              hipStream_t stream) {
  const float* memory   = (const float*)d_in[0];
  const int*   node_ids = (const int*)  d_in[1];
  const float* messages = (const float*)d_in[2];
  const float* W_ih     = (const float*)d_in[3];
  const float* W_hh     = (const float*)d_in[4];
  const float* b_ih     = (const float*)d_in[5];
  const float* b_hh     = (const float*)d_in[6];
  float* out = (float*)d_out;

  char* ws = (char*)d_ws;
  short* Wi_bf  = (short*)(ws + WI_OFF);
  short* Wh_bf  = (short*)(ws + WH_OFF);
  int*   winner = (int*)  (ws + WIN_OFF);

  // winner := -1
  hipMemsetAsync(winner, 0xFF, (size_t)NN * sizeof(int), stream);
  mark_winner_kernel<<<NUPD / 256, 256, 0, stream>>>(node_ids, winner);
  wconv_kernel<<<(384 * 256 + 384 * 128 + 255) / 256, 256, 0, stream>>>(
      W_ih, W_hh, Wi_bf, Wh_bf);

  fat_kernel<<<GRU_BLOCKS + COPY_BLOCKS, 512, 0, stream>>>(
      memory, node_ids, messages, Wi_bf, Wh_bf, b_ih, b_hh, winner, out);
}